// Round 10
// baseline (66325.720 us; speedup 1.0000x reference)
//
#include <hip/hip_runtime.h>
#include <hip/hip_cooperative_groups.h>
#include <stdint.h>
#include <math.h>

namespace cg = cooperative_groups;

#define SEQ   256
#define BATCH 8
#define HID   1024
#define VOCAB 32000
#define HB    (BATCH*HID)

typedef __attribute__((ext_vector_type(8))) short s16x8;
typedef __attribute__((ext_vector_type(4))) float f32x4;

__device__ __forceinline__ unsigned short f2bf(float f) {
    union { float f; uint32_t u; } v; v.f = f;
    uint32_t r = v.u + 0x7fffu + ((v.u >> 16) & 1u);   // RNE
    return (unsigned short)(r >> 16);
}
__device__ __forceinline__ float bf2f(unsigned short h) {
    union { float f; uint32_t u; } v; v.u = ((uint32_t)h) << 16;
    return v.f;
}

// ---------------- embedding gather ----------------
__global__ __launch_bounds__(256)
void k_embed(const int* __restrict__ idx, const float* __restrict__ emb,
             float* __restrict__ x) {
    const int row = blockIdx.x;
    const int id  = idx[row];
    const f32x4 v = *(const f32x4*)(emb + (size_t)id*HID + threadIdx.x*4);
    *(f32x4*)(x + (size_t)row*HID + threadIdx.x*4) = v;
}

// ---------------- f32 -> bf16 hi/lo split ----------------
__global__ __launch_bounds__(256)
void k_cvt(const float* __restrict__ in, unsigned short* __restrict__ hi,
           unsigned short* __restrict__ lo, int n) {
    for (int i = blockIdx.x*blockDim.x + threadIdx.x; i < n; i += gridDim.x*blockDim.x) {
        float f = in[i];
        unsigned short h = f2bf(f);
        hi[i] = h;
        lo[i] = f2bf(f - bf2f(h));
    }
}

// ---------------- f64 GEMM: C(f64) = A(f32) @ B(f32)^T ----------------
__global__ __launch_bounds__(256)
void k_gemm_f64(const float* __restrict__ A, const float* __restrict__ B,
                double* __restrict__ C, int M, int N, int K) {
    __shared__ float As[64][33];
    __shared__ float Bs[64][33];
    const int nbn = N >> 6;
    const int bm = blockIdx.x / nbn, bn = blockIdx.x % nbn;
    const int tid = threadIdx.x;
    const int tr = tid >> 4, tc = tid & 15;
    const int lr = tid >> 2, lc = (tid & 3) << 3;
    double acc[4][4];
    #pragma unroll
    for (int r = 0; r < 4; ++r)
        #pragma unroll
        for (int c = 0; c < 4; ++c) acc[r][c] = 0.0;
    const float* Ag = A + (size_t)(bm*64 + lr)*K + lc;
    const float* Bg = B + (size_t)(bn*64 + lr)*K + lc;
    for (int k0 = 0; k0 < K; k0 += 32) {
        f32x4 a0 = *(const f32x4*)(Ag + k0);
        f32x4 a1 = *(const f32x4*)(Ag + k0 + 4);
        f32x4 b0 = *(const f32x4*)(Bg + k0);
        f32x4 b1 = *(const f32x4*)(Bg + k0 + 4);
        __syncthreads();
        #pragma unroll
        for (int e = 0; e < 4; ++e) {
            As[lr][lc + e]     = a0[e];
            As[lr][lc + 4 + e] = a1[e];
            Bs[lr][lc + e]     = b0[e];
            Bs[lr][lc + 4 + e] = b1[e];
        }
        __syncthreads();
        #pragma unroll
        for (int kk = 0; kk < 32; ++kk) {
            double ad[4], bd[4];
            #pragma unroll
            for (int r = 0; r < 4; ++r) ad[r] = (double)As[tr*4 + r][kk];
            #pragma unroll
            for (int c = 0; c < 4; ++c) bd[c] = (double)Bs[tc*4 + c][kk];
            #pragma unroll
            for (int r = 0; r < 4; ++r)
                #pragma unroll
                for (int c = 0; c < 4; ++c)
                    acc[r][c] = fma(ad[r], bd[c], acc[r][c]);
        }
    }
    #pragma unroll
    for (int r = 0; r < 4; ++r) {
        double* Cr = C + (size_t)(bm*64 + tr*4 + r)*N + bn*64 + tc*4;
        #pragma unroll
        for (int c = 0; c < 4; ++c) Cr[c] = acc[r][c];
    }
}

// ------- split-bf16 MFMA GEMM (vocab projection) -------
__global__ __launch_bounds__(256)
void k_gemm3(const unsigned short* __restrict__ Ahi,
             const unsigned short* __restrict__ Alo,
             const unsigned short* __restrict__ Bhi,
             const unsigned short* __restrict__ Blo,
             float* __restrict__ C,
             const float* __restrict__ bias,
             int M, int N, int K) {
    __shared__ unsigned short Ash[128][32];
    __shared__ unsigned short Asl[128][32];
    __shared__ unsigned short Bsh[128][32];
    __shared__ unsigned short Bsl[128][32];
    const int nbn = N >> 7;
    const int bm = blockIdx.x / nbn, bn = blockIdx.x % nbn;
    const int tid = threadIdx.x;
    const int lane = tid & 63, wave = tid >> 6;
    const int wr = wave >> 1, wc = wave & 1;
    const int lrow = tid >> 2, lcol = (tid & 3) << 3;
    const size_t aoff = (size_t)(bm*128 + lrow)*K + lcol;
    const size_t boff = (size_t)(bn*128 + lrow)*K + lcol;
    const int frow = lane & 15, fk = (lane >> 4) << 3;

    f32x4 acc[4][4];
    #pragma unroll
    for (int i = 0; i < 4; ++i)
        #pragma unroll
        for (int j = 0; j < 4; ++j)
            #pragma unroll
            for (int e = 0; e < 4; ++e) acc[i][j][e] = 0.f;

    for (int k0 = 0; k0 < K; k0 += 32) {
        uint4 ah0 = *(const uint4*)(Ahi + aoff + k0);
        uint4 ah1 = *(const uint4*)(Ahi + aoff + (size_t)64*K + k0);
        uint4 al0 = *(const uint4*)(Alo + aoff + k0);
        uint4 al1 = *(const uint4*)(Alo + aoff + (size_t)64*K + k0);
        uint4 bh0 = *(const uint4*)(Bhi + boff + k0);
        uint4 bh1 = *(const uint4*)(Bhi + boff + (size_t)64*K + k0);
        uint4 bl0 = *(const uint4*)(Blo + boff + k0);
        uint4 bl1 = *(const uint4*)(Blo + boff + (size_t)64*K + k0);
        __syncthreads();
        *(uint4*)&Ash[lrow][lcol]      = ah0;
        *(uint4*)&Ash[lrow + 64][lcol] = ah1;
        *(uint4*)&Asl[lrow][lcol]      = al0;
        *(uint4*)&Asl[lrow + 64][lcol] = al1;
        *(uint4*)&Bsh[lrow][lcol]      = bh0;
        *(uint4*)&Bsh[lrow + 64][lcol] = bh1;
        *(uint4*)&Bsl[lrow][lcol]      = bl0;
        *(uint4*)&Bsl[lrow + 64][lcol] = bl1;
        __syncthreads();
        s16x8 ah[4], al[4], bh[4], bl[4];
        #pragma unroll
        for (int mi = 0; mi < 4; ++mi) {
            ah[mi] = *(const s16x8*)&Ash[wr*64 + mi*16 + frow][fk];
            al[mi] = *(const s16x8*)&Asl[wr*64 + mi*16 + frow][fk];
        }
        #pragma unroll
        for (int ni = 0; ni < 4; ++ni) {
            bh[ni] = *(const s16x8*)&Bsh[wc*64 + ni*16 + frow][fk];
            bl[ni] = *(const s16x8*)&Bsl[wc*64 + ni*16 + frow][fk];
        }
        #pragma unroll
        for (int mi = 0; mi < 4; ++mi)
            #pragma unroll
            for (int ni = 0; ni < 4; ++ni) {
                acc[mi][ni] = __builtin_amdgcn_mfma_f32_16x16x32_bf16(ah[mi], bh[ni], acc[mi][ni], 0, 0, 0);
                acc[mi][ni] = __builtin_amdgcn_mfma_f32_16x16x32_bf16(ah[mi], bl[ni], acc[mi][ni], 0, 0, 0);
                acc[mi][ni] = __builtin_amdgcn_mfma_f32_16x16x32_bf16(al[mi], bh[ni], acc[mi][ni], 0, 0, 0);
            }
    }

    #pragma unroll
    for (int mi = 0; mi < 4; ++mi) {
        const int row0 = bm*128 + wr*64 + mi*16 + ((lane >> 4) << 2);
        #pragma unroll
        for (int ni = 0; ni < 4; ++ni) {
            const int col = bn*128 + wc*64 + ni*16 + (lane & 15);
            const float bv = bias ? bias[col] : 0.f;
            #pragma unroll
            for (int r = 0; r < 4; ++r) {
                const size_t ix = (size_t)(row0 + r)*N + col;
                C[ix] = acc[mi][ni][r] + bv;
            }
        }
    }
}

// ======== single-layer sLSTM scan phase (persistent-cooperative OR per-tick) ========
// h(t) = slstm(W @ h(t-1) + G[t] + bias), G precomputed (f64 GEMM).
// 512 blocks x 256 thr. Block owns units {2bk, 2bk+1}; each unit = 2 waves,
// K-split 512 each. Per-wave: 32 VGPR weights + 32 VGPR acc (2 passes x 4 batches)
// -> ~100 VGPR total, 512 B LDS. No allocator pressure (the rounds 6-9 failure).
// coop=1: k0..k1 ticks with grid.sync between ticks (launch cooperatively!).
// coop=0: single tick per launch (fallback), k1 = k0+1.
__global__ __launch_bounds__(256)
void k_scan_phase(const float* __restrict__ W,      // [4H][H] row-major
                  const float* __restrict__ bias,   // [4H]
                  const double* __restrict__ G,     // [B*SEQ][4H] f64
                  float* hbuf, double* cbuf,        // [2][B][H] f32 parity, [B][H] f64
                  float* __restrict__ hout,         // [B*SEQ][H] f32
                  int k0, int k1, int coop) {
    cg::grid_group grid = cg::this_grid();
    __shared__ double sred[2][2][4][4];   // [unit_local][k_half][gate][batch_in_pass]
    const int bk   = blockIdx.x;          // 0..511
    const int tid  = threadIdx.x;
    const int wave = tid >> 6, lane = tid & 63;
    const int ul = wave >> 1;             // unit within block: 0,1
    const int kh = wave & 1;              // K half: 0,1
    const int u  = bk*2 + ul;             // unit in [0,1024)

    // weights -> registers: 4 gate-rows, this wave's 512-wide K half (32 VGPR)
    f32x4 w[4][2];
    #pragma unroll
    for (int g = 0; g < 4; ++g)
        #pragma unroll
        for (int jj = 0; jj < 2; ++jj)
            w[g][jj] = *(const f32x4*)(W + (size_t)(g*HID + u)*HID + kh*512 + 4*lane + 256*jj);

    for (int k = k0; k < k1; ++k) {
        if (coop && k > k0) grid.sync();
        const float* hp = hbuf + ((k + 1) & 1) * HB;      // h(t-1)
        #pragma unroll
        for (int p = 0; p < 2; ++p) {                     // 2 passes x 4 batches
            double acc[4][4];
            #pragma unroll
            for (int g = 0; g < 4; ++g)
                #pragma unroll
                for (int bb = 0; bb < 4; ++bb) acc[g][bb] = 0.0;
            #pragma unroll
            for (int jj = 0; jj < 2; ++jj) {
                const int kb = kh*512 + 4*lane + 256*jj;
                #pragma unroll
                for (int bb = 0; bb < 4; ++bb) {
                    const f32x4 hv = *(const f32x4*)(hp + (p*4 + bb)*HID + kb);
                    #pragma unroll
                    for (int g = 0; g < 4; ++g) {
                        acc[g][bb] = fma((double)w[g][jj].x, (double)hv.x, acc[g][bb]);
                        acc[g][bb] = fma((double)w[g][jj].y, (double)hv.y, acc[g][bb]);
                        acc[g][bb] = fma((double)w[g][jj].z, (double)hv.z, acc[g][bb]);
                        acc[g][bb] = fma((double)w[g][jj].w, (double)hv.w, acc[g][bb]);
                    }
                }
            }
            #pragma unroll
            for (int g = 0; g < 4; ++g)
                #pragma unroll
                for (int bb = 0; bb < 4; ++bb) {
                    double v = acc[g][bb];
                    #pragma unroll
                    for (int off = 32; off > 0; off >>= 1) v += __shfl_xor(v, off, 64);
                    acc[g][bb] = v;
                }
            if (lane == 0) {
                #pragma unroll
                for (int g = 0; g < 4; ++g)
                    #pragma unroll
                    for (int bb = 0; bb < 4; ++bb)
                        sred[ul][kh][g][bb] = acc[g][bb];
            }
            __syncthreads();
            if (kh == 1 && lane < 4) {
                const int b = p*4 + lane;
                const double* gr = G + (size_t)(b*SEQ + k)*4096;
                double tg[4];
                #pragma unroll
                for (int g = 0; g < 4; ++g)
                    tg[g] = sred[ul][0][g][lane] + sred[ul][1][g][lane]
                          + gr[g*HID + u] + (double)bias[g*HID + u];
                const double cc = exp(tg[1])*cbuf[b*HID + u] + exp(tg[0])*tanh(tg[2]);
                const double hh = tanh(cc) / (1.0 + exp(-tg[3]));
                cbuf[b*HID + u] = cc;
                hbuf[(k & 1)*HB + b*HID + u] = (float)hh;
                hout[(size_t)(b*SEQ + k)*HID + u] = (float)hh;
            }
            __syncthreads();                               // protect sred for next pass
        }
    }
}

// ---------------- GELU(exact) + residual + LayerNorm, f64 internals ----------------
__global__ __launch_bounds__(256)
void k_post(const float* __restrict__ y, const float* __restrict__ xin,
            const float* __restrict__ gamma, const float* __restrict__ beta,
            float* __restrict__ xout) {
    const int row = blockIdx.x;
    const int tid = threadIdx.x;
    const f32x4 v  = *(const f32x4*)(y   + (size_t)row*HID + tid*4);
    const f32x4 xr = *(const f32x4*)(xin + (size_t)row*HID + tid*4);
    double o[4]; double s = 0.0, q = 0.0;
    #pragma unroll
    for (int e = 0; e < 4; ++e) {
        const double t  = (double)v[e];
        const double ge = 0.5 * t * (1.0 + erf(t * 0.7071067811865476));
        const double u  = ge + (double)xr[e];
        o[e] = u; s += u; q += u*u;
    }
    #pragma unroll
    for (int off = 32; off > 0; off >>= 1) {
        s += __shfl_xor(s, off, 64);
        q += __shfl_xor(q, off, 64);
    }
    __shared__ double rs[4], rq[4];
    const int wv = tid >> 6, lane = tid & 63;
    if (lane == 0) { rs[wv] = s; rq[wv] = q; }
    __syncthreads();
    s = rs[0] + rs[1] + rs[2] + rs[3];
    q = rq[0] + rq[1] + rq[2] + rq[3];
    const double mu   = s * (1.0/HID);
    const double var  = q * (1.0/HID) - mu*mu;
    const double rstd = 1.0 / sqrt(var + 1e-5);
    f32x4 ov;
    #pragma unroll
    for (int e = 0; e < 4; ++e) {
        const int col = tid*4 + e;
        ov[e] = (float)((o[e] - mu)*rstd*(double)gamma[col] + (double)beta[col]);
    }
    *(f32x4*)(xout + (size_t)row*HID + tid*4) = ov;
}

// -------------------------------------------------------------------------
extern "C" void kernel_launch(void* const* d_in, const int* in_sizes, int n_in,
                              void* d_out, int out_size, void* d_ws, size_t ws_size,
                              hipStream_t stream) {
    const int*   idx   = (const int*)d_in[0];
    const float* emb   = (const float*)d_in[1];
    const float* w_ih  = (const float*)d_in[2];
    const float* w_hh  = (const float*)d_in[3];
    const float* bias  = (const float*)d_in[4];
    const float* ln_g  = (const float*)d_in[5];
    const float* ln_b  = (const float*)d_in[6];
    const float* out_w = (const float*)d_in[7];
    const float* out_b = (const float*)d_in[8];
    float* logits = (float*)d_out;

    char* ws = (char*)d_ws;
    size_t off = 0;
    auto alloc = [&](size_t bytes) -> char* {
        char* p = ws + off;
        off = (off + bytes + 255) & ~(size_t)255;
        return p;
    };
    const int ROWS = BATCH * SEQ;                       // 2048
    float*          X    = (float*)         alloc((size_t)ROWS*HID*4);
    unsigned short* XHI  = (unsigned short*)alloc((size_t)ROWS*HID*2);
    unsigned short* XLO  = (unsigned short*)alloc((size_t)ROWS*HID*2);
    char*           ST   =                  alloc(262144);
    char*           REG  = alloc((size_t)VOCAB*HID*2*2);                     // 131.1 MB
    // during blocks: G (67.1 MB) + H0 (8.4) + Y (8.4); final GEMM: OWHI+OWLO overlay
    double*         Gp   = (double*)REG;                                     // 67.1 MB
    float*          H0   = (float*)(REG + (size_t)ROWS*4096*8);              //  8.4 MB
    float*          Y    = (float*)(REG + (size_t)ROWS*4096*8 + (size_t)ROWS*HID*4);
    unsigned short* OWHI = (unsigned short*)REG;
    unsigned short* OWLO = (unsigned short*)(REG + (size_t)VOCAB*HID*2);

    float*  hbuf = (float*)ST;                  // [2][8][1024] f32 parity
    double* cbuf = (double*)(ST + 65536);       // [8][1024] f64

    auto run_phase = [&](const float* W, const float* bs, const double* G,
                         float* hout) {
        hipMemsetAsync(ST, 0, 131072, stream);              // zero h parity + c
        int k0 = 0, k1 = SEQ, coop = 1;
        void* ka[] = {(void*)&W, (void*)&bs, (void*)&G,
                      (void*)&hbuf, (void*)&cbuf, (void*)&hout,
                      (void*)&k0, (void*)&k1, (void*)&coop};
        hipError_t e = hipLaunchCooperativeKernel((const void*)k_scan_phase,
                                                  dim3(512), dim3(256), ka, 0, stream);
        if (e != hipSuccess) {                              // deterministic fallback
            for (int kk = 0; kk < SEQ; ++kk)
                k_scan_phase<<<512, 256, 0, stream>>>(W, bs, G, hbuf, cbuf, hout,
                                                      kk, kk + 1, 0);
        }
    };

    k_embed<<<ROWS, 256, 0, stream>>>(idx, emb, X);

    for (int blk = 0; blk < 2; ++blk) {
        const float* wih0 = w_ih + (size_t)blk*2*4096*HID;
        const float* wih1 = wih0 + (size_t)4096*HID;
        const float* whh0 = w_hh + (size_t)blk*2*4096*HID;
        const float* whh1 = whh0 + (size_t)4096*HID;
        const float* b0 = bias + (size_t)blk*2*4096;
        const float* b1 = b0 + 4096;

        // G = x @ w_ih0^T (f64), phase A: layer-0 scan -> H0
        k_gemm_f64<<<(ROWS/64)*(4096/64), 256, 0, stream>>>(X, wih0, Gp,
                                                            ROWS, 4096, HID);
        run_phase(whh0, b0, Gp, H0);

        // G = H0 @ w_ih1^T (f64, overwrites consumed G), phase B: layer-1 -> Y
        k_gemm_f64<<<(ROWS/64)*(4096/64), 256, 0, stream>>>(H0, wih1, Gp,
                                                            ROWS, 4096, HID);
        run_phase(whh1, b1, Gp, Y);

        k_post<<<ROWS, 256, 0, stream>>>(Y, X, ln_g + blk*HID, ln_b + blk*HID, X);
    }

    // logits = x @ out_w^T + out_b in split-bf16 (~f32 accuracy; not amplified)
    k_cvt<<<1024, 256, 0, stream>>>(X, XHI, XLO, ROWS*HID);
    k_cvt<<<4096, 256, 0, stream>>>(out_w, OWHI, OWLO, VOCAB*HID);
    k_gemm3<<<16*250, 256, 0, stream>>>(XHI, XLO, OWHI, OWLO, logits, out_b,
                                        ROWS, VOCAB, HID);
}

// Round 11
// 23276.160 us; speedup vs baseline: 2.8495x; 2.8495x over previous
//
#include <hip/hip_runtime.h>
#include <hip/hip_cooperative_groups.h>
#include <stdint.h>
#include <math.h>

#define SEQ   256
#define BATCH 8
#define HID   1024
#define VOCAB 32000
#define HB    (BATCH*HID)

typedef __attribute__((ext_vector_type(8))) short s16x8;
typedef __attribute__((ext_vector_type(4))) float f32x4;

__device__ __forceinline__ unsigned short f2bf(float f) {
    union { float f; uint32_t u; } v; v.f = f;
    uint32_t r = v.u + 0x7fffu + ((v.u >> 16) & 1u);   // RNE
    return (unsigned short)(r >> 16);
}
__device__ __forceinline__ float bf2f(unsigned short h) {
    union { float f; uint32_t u; } v; v.u = ((uint32_t)h) << 16;
    return v.f;
}

// agent-scope (device-coherent, LLC) f32x4 load assembled from scalar atomics
__device__ __forceinline__ f32x4 ld4_agent(const float* p) {
    f32x4 v;
    v.x = __hip_atomic_load(p + 0, __ATOMIC_RELAXED, __HIP_MEMORY_SCOPE_AGENT);
    v.y = __hip_atomic_load(p + 1, __ATOMIC_RELAXED, __HIP_MEMORY_SCOPE_AGENT);
    v.z = __hip_atomic_load(p + 2, __ATOMIC_RELAXED, __HIP_MEMORY_SCOPE_AGENT);
    v.w = __hip_atomic_load(p + 3, __ATOMIC_RELAXED, __HIP_MEMORY_SCOPE_AGENT);
    return v;
}

// ---------------- embedding gather ----------------
__global__ __launch_bounds__(256)
void k_embed(const int* __restrict__ idx, const float* __restrict__ emb,
             float* __restrict__ x) {
    const int row = blockIdx.x;
    const int id  = idx[row];
    const f32x4 v = *(const f32x4*)(emb + (size_t)id*HID + threadIdx.x*4);
    *(f32x4*)(x + (size_t)row*HID + threadIdx.x*4) = v;
}

// ---------------- f32 -> bf16 hi/lo split ----------------
__global__ __launch_bounds__(256)
void k_cvt(const float* __restrict__ in, unsigned short* __restrict__ hi,
           unsigned short* __restrict__ lo, int n) {
    for (int i = blockIdx.x*blockDim.x + threadIdx.x; i < n; i += gridDim.x*blockDim.x) {
        float f = in[i];
        unsigned short h = f2bf(f);
        hi[i] = h;
        lo[i] = f2bf(f - bf2f(h));
    }
}

// ---------------- f64 GEMM: C(f64) = A(f32) @ B(f32)^T ----------------
__global__ __launch_bounds__(256)
void k_gemm_f64(const float* __restrict__ A, const float* __restrict__ B,
                double* __restrict__ C, int M, int N, int K) {
    __shared__ float As[64][33];
    __shared__ float Bs[64][33];
    const int nbn = N >> 6;
    const int bm = blockIdx.x / nbn, bn = blockIdx.x % nbn;
    const int tid = threadIdx.x;
    const int tr = tid >> 4, tc = tid & 15;
    const int lr = tid >> 2, lc = (tid & 3) << 3;
    double acc[4][4];
    #pragma unroll
    for (int r = 0; r < 4; ++r)
        #pragma unroll
        for (int c = 0; c < 4; ++c) acc[r][c] = 0.0;
    const float* Ag = A + (size_t)(bm*64 + lr)*K + lc;
    const float* Bg = B + (size_t)(bn*64 + lr)*K + lc;
    for (int k0 = 0; k0 < K; k0 += 32) {
        f32x4 a0 = *(const f32x4*)(Ag + k0);
        f32x4 a1 = *(const f32x4*)(Ag + k0 + 4);
        f32x4 b0 = *(const f32x4*)(Bg + k0);
        f32x4 b1 = *(const f32x4*)(Bg + k0 + 4);
        __syncthreads();
        #pragma unroll
        for (int e = 0; e < 4; ++e) {
            As[lr][lc + e]     = a0[e];
            As[lr][lc + 4 + e] = a1[e];
            Bs[lr][lc + e]     = b0[e];
            Bs[lr][lc + 4 + e] = b1[e];
        }
        __syncthreads();
        #pragma unroll
        for (int kk = 0; kk < 32; ++kk) {
            double ad[4], bd[4];
            #pragma unroll
            for (int r = 0; r < 4; ++r) ad[r] = (double)As[tr*4 + r][kk];
            #pragma unroll
            for (int c = 0; c < 4; ++c) bd[c] = (double)Bs[tc*4 + c][kk];
            #pragma unroll
            for (int r = 0; r < 4; ++r)
                #pragma unroll
                for (int c = 0; c < 4; ++c)
                    acc[r][c] = fma(ad[r], bd[c], acc[r][c]);
        }
    }
    #pragma unroll
    for (int r = 0; r < 4; ++r) {
        double* Cr = C + (size_t)(bm*64 + tr*4 + r)*N + bn*64 + tc*4;
        #pragma unroll
        for (int c = 0; c < 4; ++c) Cr[c] = acc[r][c];
    }
}

// ------- split-bf16 MFMA GEMM (vocab projection) -------
__global__ __launch_bounds__(256)
void k_gemm3(const unsigned short* __restrict__ Ahi,
             const unsigned short* __restrict__ Alo,
             const unsigned short* __restrict__ Bhi,
             const unsigned short* __restrict__ Blo,
             float* __restrict__ C,
             const float* __restrict__ bias,
             int M, int N, int K) {
    __shared__ unsigned short Ash[128][32];
    __shared__ unsigned short Asl[128][32];
    __shared__ unsigned short Bsh[128][32];
    __shared__ unsigned short Bsl[128][32];
    const int nbn = N >> 7;
    const int bm = blockIdx.x / nbn, bn = blockIdx.x % nbn;
    const int tid = threadIdx.x;
    const int lane = tid & 63, wave = tid >> 6;
    const int wr = wave >> 1, wc = wave & 1;
    const int lrow = tid >> 2, lcol = (tid & 3) << 3;
    const size_t aoff = (size_t)(bm*128 + lrow)*K + lcol;
    const size_t boff = (size_t)(bn*128 + lrow)*K + lcol;
    const int frow = lane & 15, fk = (lane >> 4) << 3;

    f32x4 acc[4][4];
    #pragma unroll
    for (int i = 0; i < 4; ++i)
        #pragma unroll
        for (int j = 0; j < 4; ++j)
            #pragma unroll
            for (int e = 0; e < 4; ++e) acc[i][j][e] = 0.f;

    for (int k0 = 0; k0 < K; k0 += 32) {
        uint4 ah0 = *(const uint4*)(Ahi + aoff + k0);
        uint4 ah1 = *(const uint4*)(Ahi + aoff + (size_t)64*K + k0);
        uint4 al0 = *(const uint4*)(Alo + aoff + k0);
        uint4 al1 = *(const uint4*)(Alo + aoff + (size_t)64*K + k0);
        uint4 bh0 = *(const uint4*)(Bhi + boff + k0);
        uint4 bh1 = *(const uint4*)(Bhi + boff + (size_t)64*K + k0);
        uint4 bl0 = *(const uint4*)(Blo + boff + k0);
        uint4 bl1 = *(const uint4*)(Blo + boff + (size_t)64*K + k0);
        __syncthreads();
        *(uint4*)&Ash[lrow][lcol]      = ah0;
        *(uint4*)&Ash[lrow + 64][lcol] = ah1;
        *(uint4*)&Asl[lrow][lcol]      = al0;
        *(uint4*)&Asl[lrow + 64][lcol] = al1;
        *(uint4*)&Bsh[lrow][lcol]      = bh0;
        *(uint4*)&Bsh[lrow + 64][lcol] = bh1;
        *(uint4*)&Bsl[lrow][lcol]      = bl0;
        *(uint4*)&Bsl[lrow + 64][lcol] = bl1;
        __syncthreads();
        s16x8 ah[4], al[4], bh[4], bl[4];
        #pragma unroll
        for (int mi = 0; mi < 4; ++mi) {
            ah[mi] = *(const s16x8*)&Ash[wr*64 + mi*16 + frow][fk];
            al[mi] = *(const s16x8*)&Asl[wr*64 + mi*16 + frow][fk];
        }
        #pragma unroll
        for (int ni = 0; ni < 4; ++ni) {
            bh[ni] = *(const s16x8*)&Bsh[wc*64 + ni*16 + frow][fk];
            bl[ni] = *(const s16x8*)&Bsl[wc*64 + ni*16 + frow][fk];
        }
        #pragma unroll
        for (int mi = 0; mi < 4; ++mi)
            #pragma unroll
            for (int ni = 0; ni < 4; ++ni) {
                acc[mi][ni] = __builtin_amdgcn_mfma_f32_16x16x32_bf16(ah[mi], bh[ni], acc[mi][ni], 0, 0, 0);
                acc[mi][ni] = __builtin_amdgcn_mfma_f32_16x16x32_bf16(ah[mi], bl[ni], acc[mi][ni], 0, 0, 0);
                acc[mi][ni] = __builtin_amdgcn_mfma_f32_16x16x32_bf16(al[mi], bh[ni], acc[mi][ni], 0, 0, 0);
            }
    }

    #pragma unroll
    for (int mi = 0; mi < 4; ++mi) {
        const int row0 = bm*128 + wr*64 + mi*16 + ((lane >> 4) << 2);
        #pragma unroll
        for (int ni = 0; ni < 4; ++ni) {
            const int col = bn*128 + wc*64 + ni*16 + (lane & 15);
            const float bv = bias ? bias[col] : 0.f;
            #pragma unroll
            for (int r = 0; r < 4; ++r) {
                const size_t ix = (size_t)(row0 + r)*N + col;
                C[ix] = acc[mi][ni][r] + bv;
            }
        }
    }
}

// ======== single-layer sLSTM scan phase, custom LLC slot-barrier ========
// Round-10 profile: grid.sync() costs ~61 us/tick (VALUBusy 5%, HBM 0.4%,
// 16.4 ms / 256 ticks) -- it bulk-flushes non-coherent per-XCD L2s. Here the
// ONLY cross-block data (h, 32 KB/tick) moves via agent-scope relaxed atomics
// (LLC-coherent, L2-bypassing), so no flush is needed. Barrier: block bk
// writes tick# to slots[bk] (no RMW contention); each thread polls 2 slots.
// __syncthreads() before arrival drains h-stores (vmcnt(0) precedes s_barrier).
// Bounded spin: visibility failure -> wrong answer fast, never a hang.
// coop=1 requires cooperative launch (co-residency); coop=0 = per-tick fallback.
__global__ __launch_bounds__(256)
void k_scan_phase(const float* __restrict__ W,      // [4H][H] row-major
                  const float* __restrict__ bias,   // [4H]
                  const double* __restrict__ G,     // [B*SEQ][4H] f64
                  float* hbuf, double* cbuf,        // [2][B][H] f32 parity, [B][H] f64
                  float* __restrict__ hout,         // [B*SEQ][H] f32
                  unsigned* slots,                  // [512] barrier slots
                  int k0, int k1, int coop) {
    __shared__ double sred[2][2][4][4];   // [unit_local][k_half][gate][batch_in_pass]
    const int bk   = blockIdx.x;          // 0..511
    const int tid  = threadIdx.x;
    const int wave = tid >> 6, lane = tid & 63;
    const int ul = wave >> 1;             // unit within block: 0,1
    const int kh = wave & 1;              // K half: 0,1
    const int u  = bk*2 + ul;             // unit in [0,1024)

    // weights -> registers: 4 gate-rows, this wave's 512-wide K half (32 VGPR)
    f32x4 w[4][2];
    #pragma unroll
    for (int g = 0; g < 4; ++g)
        #pragma unroll
        for (int jj = 0; jj < 2; ++jj)
            w[g][jj] = *(const f32x4*)(W + (size_t)(g*HID + u)*HID + kh*512 + 4*lane + 256*jj);

    for (int k = k0; k < k1; ++k) {
        if (coop && k > k0) {
            // wait: all 512 blocks posted tick k-1
            const unsigned tgt = (unsigned)(k - k0);
            unsigned sp = 0;
            while (__hip_atomic_load(&slots[tid], __ATOMIC_RELAXED,
                                     __HIP_MEMORY_SCOPE_AGENT) < tgt && ++sp < (1u<<17))
                __builtin_amdgcn_s_sleep(2);
            sp = 0;
            while (__hip_atomic_load(&slots[tid + 256], __ATOMIC_RELAXED,
                                     __HIP_MEMORY_SCOPE_AGENT) < tgt && ++sp < (1u<<17))
                __builtin_amdgcn_s_sleep(2);
            __syncthreads();
        }
        const float* hp = hbuf + ((k + 1) & 1) * HB;      // h(t-1)
        #pragma unroll
        for (int p = 0; p < 2; ++p) {                     // 2 passes x 4 batches
            double acc[4][4];
            #pragma unroll
            for (int g = 0; g < 4; ++g)
                #pragma unroll
                for (int bb = 0; bb < 4; ++bb) acc[g][bb] = 0.0;
            #pragma unroll
            for (int jj = 0; jj < 2; ++jj) {
                const int kb = kh*512 + 4*lane + 256*jj;
                #pragma unroll
                for (int bb = 0; bb < 4; ++bb) {
                    const f32x4 hv = ld4_agent(hp + (p*4 + bb)*HID + kb);
                    #pragma unroll
                    for (int g = 0; g < 4; ++g) {
                        acc[g][bb] = fma((double)w[g][jj].x, (double)hv.x, acc[g][bb]);
                        acc[g][bb] = fma((double)w[g][jj].y, (double)hv.y, acc[g][bb]);
                        acc[g][bb] = fma((double)w[g][jj].z, (double)hv.z, acc[g][bb]);
                        acc[g][bb] = fma((double)w[g][jj].w, (double)hv.w, acc[g][bb]);
                    }
                }
            }
            #pragma unroll
            for (int g = 0; g < 4; ++g)
                #pragma unroll
                for (int bb = 0; bb < 4; ++bb) {
                    double v = acc[g][bb];
                    #pragma unroll
                    for (int off = 32; off > 0; off >>= 1) v += __shfl_xor(v, off, 64);
                    acc[g][bb] = v;
                }
            if (lane == 0) {
                #pragma unroll
                for (int g = 0; g < 4; ++g)
                    #pragma unroll
                    for (int bb = 0; bb < 4; ++bb)
                        sred[ul][kh][g][bb] = acc[g][bb];
            }
            __syncthreads();
            if (kh == 1 && lane < 4) {
                const int b = p*4 + lane;
                const double* gr = G + (size_t)(b*SEQ + k)*4096;
                double tg[4];
                #pragma unroll
                for (int g = 0; g < 4; ++g)
                    tg[g] = sred[ul][0][g][lane] + sred[ul][1][g][lane]
                          + gr[g*HID + u] + (double)bias[g*HID + u];
                const double cc = exp(tg[1])*cbuf[b*HID + u] + exp(tg[0])*tanh(tg[2]);
                const double hh = tanh(cc) / (1.0 + exp(-tg[3]));
                cbuf[b*HID + u] = cc;
                __hip_atomic_store(&hbuf[(k & 1)*HB + b*HID + u], (float)hh,
                                   __ATOMIC_RELAXED, __HIP_MEMORY_SCOPE_AGENT);
                hout[(size_t)(b*SEQ + k)*HID + u] = (float)hh;
            }
            __syncthreads();                               // protect sred for next pass
        }
        if (coop) {
            __syncthreads();          // drains this block's h-stores (vmcnt(0) + s_barrier)
            if (tid == 0)
                __hip_atomic_store(&slots[bk], (unsigned)(k - k0 + 1),
                                   __ATOMIC_RELAXED, __HIP_MEMORY_SCOPE_AGENT);
        }
    }
}

// ---------------- GELU(exact) + residual + LayerNorm, f64 internals ----------------
__global__ __launch_bounds__(256)
void k_post(const float* __restrict__ y, const float* __restrict__ xin,
            const float* __restrict__ gamma, const float* __restrict__ beta,
            float* __restrict__ xout) {
    const int row = blockIdx.x;
    const int tid = threadIdx.x;
    const f32x4 v  = *(const f32x4*)(y   + (size_t)row*HID + tid*4);
    const f32x4 xr = *(const f32x4*)(xin + (size_t)row*HID + tid*4);
    double o[4]; double s = 0.0, q = 0.0;
    #pragma unroll
    for (int e = 0; e < 4; ++e) {
        const double t  = (double)v[e];
        const double ge = 0.5 * t * (1.0 + erf(t * 0.7071067811865476));
        const double u  = ge + (double)xr[e];
        o[e] = u; s += u; q += u*u;
    }
    #pragma unroll
    for (int off = 32; off > 0; off >>= 1) {
        s += __shfl_xor(s, off, 64);
        q += __shfl_xor(q, off, 64);
    }
    __shared__ double rs[4], rq[4];
    const int wv = tid >> 6, lane = tid & 63;
    if (lane == 0) { rs[wv] = s; rq[wv] = q; }
    __syncthreads();
    s = rs[0] + rs[1] + rs[2] + rs[3];
    q = rq[0] + rq[1] + rq[2] + rq[3];
    const double mu   = s * (1.0/HID);
    const double var  = q * (1.0/HID) - mu*mu;
    const double rstd = 1.0 / sqrt(var + 1e-5);
    f32x4 ov;
    #pragma unroll
    for (int e = 0; e < 4; ++e) {
        const int col = tid*4 + e;
        ov[e] = (float)((o[e] - mu)*rstd*(double)gamma[col] + (double)beta[col]);
    }
    *(f32x4*)(xout + (size_t)row*HID + tid*4) = ov;
}

// -------------------------------------------------------------------------
extern "C" void kernel_launch(void* const* d_in, const int* in_sizes, int n_in,
                              void* d_out, int out_size, void* d_ws, size_t ws_size,
                              hipStream_t stream) {
    const int*   idx   = (const int*)d_in[0];
    const float* emb   = (const float*)d_in[1];
    const float* w_ih  = (const float*)d_in[2];
    const float* w_hh  = (const float*)d_in[3];
    const float* bias  = (const float*)d_in[4];
    const float* ln_g  = (const float*)d_in[5];
    const float* ln_b  = (const float*)d_in[6];
    const float* out_w = (const float*)d_in[7];
    const float* out_b = (const float*)d_in[8];
    float* logits = (float*)d_out;

    char* ws = (char*)d_ws;
    size_t off = 0;
    auto alloc = [&](size_t bytes) -> char* {
        char* p = ws + off;
        off = (off + bytes + 255) & ~(size_t)255;
        return p;
    };
    const int ROWS = BATCH * SEQ;                       // 2048
    float*          X    = (float*)         alloc((size_t)ROWS*HID*4);
    unsigned short* XHI  = (unsigned short*)alloc((size_t)ROWS*HID*2);
    unsigned short* XLO  = (unsigned short*)alloc((size_t)ROWS*HID*2);
    char*           ST   =                  alloc(262144);
    char*           REG  = alloc((size_t)VOCAB*HID*2*2);                     // 131.1 MB
    // during blocks: G (67.1 MB) + H0 (8.4) + Y (8.4); final GEMM: OWHI+OWLO overlay
    double*         Gp   = (double*)REG;                                     // 67.1 MB
    float*          H0   = (float*)(REG + (size_t)ROWS*4096*8);              //  8.4 MB
    float*          Y    = (float*)(REG + (size_t)ROWS*4096*8 + (size_t)ROWS*HID*4);
    unsigned short* OWHI = (unsigned short*)REG;
    unsigned short* OWLO = (unsigned short*)(REG + (size_t)VOCAB*HID*2);

    float*    hbuf  = (float*)ST;                  // [2][8][1024] f32 parity  (64 KB)
    double*   cbuf  = (double*)(ST + 65536);       // [8][1024] f64            (64 KB)
    unsigned* slots = (unsigned*)(ST + 131072);    // [512] barrier            ( 2 KB)

    auto run_phase = [&](const float* W, const float* bs, const double* G,
                         float* hout) {
        hipMemsetAsync(ST, 0, 133120, stream);     // zero h parity + c + slots
        int k0 = 0, k1 = SEQ, coop = 1;
        void* ka[] = {(void*)&W, (void*)&bs, (void*)&G,
                      (void*)&hbuf, (void*)&cbuf, (void*)&hout, (void*)&slots,
                      (void*)&k0, (void*)&k1, (void*)&coop};
        hipError_t e = hipLaunchCooperativeKernel((const void*)k_scan_phase,
                                                  dim3(512), dim3(256), ka, 0, stream);
        if (e != hipSuccess) {                     // deterministic fallback
            for (int kk = 0; kk < SEQ; ++kk)
                k_scan_phase<<<512, 256, 0, stream>>>(W, bs, G, hbuf, cbuf, hout,
                                                      slots, kk, kk + 1, 0);
        }
    };

    k_embed<<<ROWS, 256, 0, stream>>>(idx, emb, X);

    for (int blk = 0; blk < 2; ++blk) {
        const float* wih0 = w_ih + (size_t)blk*2*4096*HID;
        const float* wih1 = wih0 + (size_t)4096*HID;
        const float* whh0 = w_hh + (size_t)blk*2*4096*HID;
        const float* whh1 = whh0 + (size_t)4096*HID;
        const float* b0 = bias + (size_t)blk*2*4096;
        const float* b1 = b0 + 4096;

        // G = x @ w_ih0^T (f64), phase A: layer-0 scan -> H0
        k_gemm_f64<<<(ROWS/64)*(4096/64), 256, 0, stream>>>(X, wih0, Gp,
                                                            ROWS, 4096, HID);
        run_phase(whh0, b0, Gp, H0);

        // G = H0 @ w_ih1^T (f64, overwrites consumed G), phase B: layer-1 -> Y
        k_gemm_f64<<<(ROWS/64)*(4096/64), 256, 0, stream>>>(H0, wih1, Gp,
                                                            ROWS, 4096, HID);
        run_phase(whh1, b1, Gp, Y);

        k_post<<<ROWS, 256, 0, stream>>>(Y, X, ln_g + blk*HID, ln_b + blk*HID, X);
    }

    // logits = x @ out_w^T + out_b in split-bf16 (~f32 accuracy; not amplified)
    k_cvt<<<1024, 256, 0, stream>>>(X, XHI, XLO, ROWS*HID);
    k_cvt<<<4096, 256, 0, stream>>>(out_w, OWHI, OWLO, VOCAB*HID);
    k_gemm3<<<16*250, 256, 0, stream>>>(XHI, XLO, OWHI, OWLO, logits, out_b,
                                        ROWS, VOCAB, HID);
}

// Round 12
// 22085.500 us; speedup vs baseline: 3.0031x; 1.0539x over previous
//
#include <hip/hip_runtime.h>
#include <hip/hip_cooperative_groups.h>
#include <stdint.h>
#include <math.h>

#define SEQ   256
#define BATCH 8
#define HID   1024
#define VOCAB 32000
#define HB    (BATCH*HID)

typedef __attribute__((ext_vector_type(8))) short s16x8;
typedef __attribute__((ext_vector_type(4))) float f32x4;

__device__ __forceinline__ unsigned short f2bf(float f) {
    union { float f; uint32_t u; } v; v.f = f;
    uint32_t r = v.u + 0x7fffu + ((v.u >> 16) & 1u);   // RNE
    return (unsigned short)(r >> 16);
}
__device__ __forceinline__ float bf2f(unsigned short h) {
    union { float f; uint32_t u; } v; v.u = ((uint32_t)h) << 16;
    return v.f;
}

// device-coherent (LLC, L1/L2-bypassing) 16B load — vector form of the
// agent-scope atomic-load encoding (sc0 sc1). Caller must s_waitcnt vmcnt(0)
// before using the result.
__device__ __forceinline__ f32x4 ld16_dc(const float* p) {
    f32x4 v;
    asm volatile("global_load_dwordx4 %0, %1, off sc0 sc1"
                 : "=v"(v) : "v"(p) : "memory");
    return v;
}

// ---------------- embedding gather ----------------
__global__ __launch_bounds__(256)
void k_embed(const int* __restrict__ idx, const float* __restrict__ emb,
             float* __restrict__ x) {
    const int row = blockIdx.x;
    const int id  = idx[row];
    const f32x4 v = *(const f32x4*)(emb + (size_t)id*HID + threadIdx.x*4);
    *(f32x4*)(x + (size_t)row*HID + threadIdx.x*4) = v;
}

// ---------------- f32 -> bf16 hi/lo split ----------------
__global__ __launch_bounds__(256)
void k_cvt(const float* __restrict__ in, unsigned short* __restrict__ hi,
           unsigned short* __restrict__ lo, int n) {
    for (int i = blockIdx.x*blockDim.x + threadIdx.x; i < n; i += gridDim.x*blockDim.x) {
        float f = in[i];
        unsigned short h = f2bf(f);
        hi[i] = h;
        lo[i] = f2bf(f - bf2f(h));
    }
}

// ---------------- f64 GEMM: C(f64) = A(f32) @ B(f32)^T ----------------
__global__ __launch_bounds__(256)
void k_gemm_f64(const float* __restrict__ A, const float* __restrict__ B,
                double* __restrict__ C, int M, int N, int K) {
    __shared__ float As[64][33];
    __shared__ float Bs[64][33];
    const int nbn = N >> 6;
    const int bm = blockIdx.x / nbn, bn = blockIdx.x % nbn;
    const int tid = threadIdx.x;
    const int tr = tid >> 4, tc = tid & 15;
    const int lr = tid >> 2, lc = (tid & 3) << 3;
    double acc[4][4];
    #pragma unroll
    for (int r = 0; r < 4; ++r)
        #pragma unroll
        for (int c = 0; c < 4; ++c) acc[r][c] = 0.0;
    const float* Ag = A + (size_t)(bm*64 + lr)*K + lc;
    const float* Bg = B + (size_t)(bn*64 + lr)*K + lc;
    for (int k0 = 0; k0 < K; k0 += 32) {
        f32x4 a0 = *(const f32x4*)(Ag + k0);
        f32x4 a1 = *(const f32x4*)(Ag + k0 + 4);
        f32x4 b0 = *(const f32x4*)(Bg + k0);
        f32x4 b1 = *(const f32x4*)(Bg + k0 + 4);
        __syncthreads();
        #pragma unroll
        for (int e = 0; e < 4; ++e) {
            As[lr][lc + e]     = a0[e];
            As[lr][lc + 4 + e] = a1[e];
            Bs[lr][lc + e]     = b0[e];
            Bs[lr][lc + 4 + e] = b1[e];
        }
        __syncthreads();
        #pragma unroll
        for (int kk = 0; kk < 32; ++kk) {
            double ad[4], bd[4];
            #pragma unroll
            for (int r = 0; r < 4; ++r) ad[r] = (double)As[tr*4 + r][kk];
            #pragma unroll
            for (int c = 0; c < 4; ++c) bd[c] = (double)Bs[tc*4 + c][kk];
            #pragma unroll
            for (int r = 0; r < 4; ++r)
                #pragma unroll
                for (int c = 0; c < 4; ++c)
                    acc[r][c] = fma(ad[r], bd[c], acc[r][c]);
        }
    }
    #pragma unroll
    for (int r = 0; r < 4; ++r) {
        double* Cr = C + (size_t)(bm*64 + tr*4 + r)*N + bn*64 + tc*4;
        #pragma unroll
        for (int c = 0; c < 4; ++c) Cr[c] = acc[r][c];
    }
}

// ------- split-bf16 MFMA GEMM (vocab projection) -------
__global__ __launch_bounds__(256)
void k_gemm3(const unsigned short* __restrict__ Ahi,
             const unsigned short* __restrict__ Alo,
             const unsigned short* __restrict__ Bhi,
             const unsigned short* __restrict__ Blo,
             float* __restrict__ C,
             const float* __restrict__ bias,
             int M, int N, int K) {
    __shared__ unsigned short Ash[128][32];
    __shared__ unsigned short Asl[128][32];
    __shared__ unsigned short Bsh[128][32];
    __shared__ unsigned short Bsl[128][32];
    const int nbn = N >> 7;
    const int bm = blockIdx.x / nbn, bn = blockIdx.x % nbn;
    const int tid = threadIdx.x;
    const int lane = tid & 63, wave = tid >> 6;
    const int wr = wave >> 1, wc = wave & 1;
    const int lrow = tid >> 2, lcol = (tid & 3) << 3;
    const size_t aoff = (size_t)(bm*128 + lrow)*K + lcol;
    const size_t boff = (size_t)(bn*128 + lrow)*K + lcol;
    const int frow = lane & 15, fk = (lane >> 4) << 3;

    f32x4 acc[4][4];
    #pragma unroll
    for (int i = 0; i < 4; ++i)
        #pragma unroll
        for (int j = 0; j < 4; ++j)
            #pragma unroll
            for (int e = 0; e < 4; ++e) acc[i][j][e] = 0.f;

    for (int k0 = 0; k0 < K; k0 += 32) {
        uint4 ah0 = *(const uint4*)(Ahi + aoff + k0);
        uint4 ah1 = *(const uint4*)(Ahi + aoff + (size_t)64*K + k0);
        uint4 al0 = *(const uint4*)(Alo + aoff + k0);
        uint4 al1 = *(const uint4*)(Alo + aoff + (size_t)64*K + k0);
        uint4 bh0 = *(const uint4*)(Bhi + boff + k0);
        uint4 bh1 = *(const uint4*)(Bhi + boff + (size_t)64*K + k0);
        uint4 bl0 = *(const uint4*)(Blo + boff + k0);
        uint4 bl1 = *(const uint4*)(Blo + boff + (size_t)64*K + k0);
        __syncthreads();
        *(uint4*)&Ash[lrow][lcol]      = ah0;
        *(uint4*)&Ash[lrow + 64][lcol] = ah1;
        *(uint4*)&Asl[lrow][lcol]      = al0;
        *(uint4*)&Asl[lrow + 64][lcol] = al1;
        *(uint4*)&Bsh[lrow][lcol]      = bh0;
        *(uint4*)&Bsh[lrow + 64][lcol] = bh1;
        *(uint4*)&Bsl[lrow][lcol]      = bl0;
        *(uint4*)&Bsl[lrow + 64][lcol] = bl1;
        __syncthreads();
        s16x8 ah[4], al[4], bh[4], bl[4];
        #pragma unroll
        for (int mi = 0; mi < 4; ++mi) {
            ah[mi] = *(const s16x8*)&Ash[wr*64 + mi*16 + frow][fk];
            al[mi] = *(const s16x8*)&Asl[wr*64 + mi*16 + frow][fk];
        }
        #pragma unroll
        for (int ni = 0; ni < 4; ++ni) {
            bh[ni] = *(const s16x8*)&Bsh[wc*64 + ni*16 + frow][fk];
            bl[ni] = *(const s16x8*)&Bsl[wc*64 + ni*16 + frow][fk];
        }
        #pragma unroll
        for (int mi = 0; mi < 4; ++mi)
            #pragma unroll
            for (int ni = 0; ni < 4; ++ni) {
                acc[mi][ni] = __builtin_amdgcn_mfma_f32_16x16x32_bf16(ah[mi], bh[ni], acc[mi][ni], 0, 0, 0);
                acc[mi][ni] = __builtin_amdgcn_mfma_f32_16x16x32_bf16(ah[mi], bl[ni], acc[mi][ni], 0, 0, 0);
                acc[mi][ni] = __builtin_amdgcn_mfma_f32_16x16x32_bf16(al[mi], bh[ni], acc[mi][ni], 0, 0, 0);
            }
    }

    #pragma unroll
    for (int mi = 0; mi < 4; ++mi) {
        const int row0 = bm*128 + wr*64 + mi*16 + ((lane >> 4) << 2);
        #pragma unroll
        for (int ni = 0; ni < 4; ++ni) {
            const int col = bn*128 + wc*64 + ni*16 + (lane & 15);
            const float bv = bias ? bias[col] : 0.f;
            #pragma unroll
            for (int r = 0; r < 4; ++r) {
                const size_t ix = (size_t)(row0 + r)*N + col;
                C[ix] = acc[mi][ni][r] + bv;
            }
        }
    }
}

// ======== single-layer sLSTM scan phase, LLC slot-barrier + LDS-staged h ========
// Round-11 profile: tick = 21 us, compute ~3 us -> residual was the h-load path
// (64 scalar agent loads/thread, ~700 ns each, 2 waves/SIMD) + 2 sequential polls.
// Here: h(t-1) (32 KB) is staged into LDS once per tick with 4 CONCURRENT
// device-coherent dwordx4 loads per thread (sc0 sc1 = vector form of the
// agent atomic-load path; one vmcnt(0) drain), inner loop reads LDS.
// 256 blocks x 512 thr (1 block/CU): halves redundant LLC traffic; barrier is a
// single parallel poll (tid<256 each polls one slot). Math order per
// accumulator identical to rounds 4-11 -> bitwise-same gates.
__global__ __launch_bounds__(512)
void k_scan_phase(const float* __restrict__ W,      // [4H][H] row-major
                  const float* __restrict__ bias,   // [4H]
                  const double* __restrict__ G,     // [B*SEQ][4H] f64
                  float* hbuf, double* cbuf,        // [2][B][H] f32 parity, [B][H] f64
                  float* __restrict__ hout,         // [B*SEQ][H] f32
                  unsigned* slots,                  // [256] barrier slots
                  int k0, int k1, int coop) {
    __shared__ float  shh[HB];            // 32 KB staged h(t-1)
    __shared__ double sred[4][2][4][4];   // [unit_local][k_half][gate][batch_in_pass]
    const int bk   = blockIdx.x;          // 0..255
    const int tid  = threadIdx.x;         // 0..511
    const int wave = tid >> 6, lane = tid & 63;
    const int ul = wave >> 1;             // unit within block: 0..3
    const int kh = wave & 1;              // K half: 0,1
    const int u  = bk*4 + ul;             // unit in [0,1024)

    // weights -> registers: 4 gate-rows, this wave's 512-wide K half (32 VGPR)
    f32x4 w[4][2];
    #pragma unroll
    for (int g = 0; g < 4; ++g)
        #pragma unroll
        for (int jj = 0; jj < 2; ++jj)
            w[g][jj] = *(const f32x4*)(W + (size_t)(g*HID + u)*HID + kh*512 + 4*lane + 256*jj);

    for (int k = k0; k < k1; ++k) {
        if (coop && k > k0) {
            const unsigned tgt = (unsigned)(k - k0);
            if (tid < 256) {
                unsigned sp = 0;
                while (__hip_atomic_load(&slots[tid], __ATOMIC_RELAXED,
                                         __HIP_MEMORY_SCOPE_AGENT) < tgt && ++sp < (1u<<17))
                    __builtin_amdgcn_s_sleep(2);
            }
            __syncthreads();
        }
        // ---- stage h(t-1) -> LDS: 4 concurrent device-coherent 16B loads ----
        {
            const float* hp = hbuf + ((k + 1) & 1) * HB;
            f32x4 t0 = ld16_dc(hp + (0*512 + tid)*4);
            f32x4 t1 = ld16_dc(hp + (1*512 + tid)*4);
            f32x4 t2 = ld16_dc(hp + (2*512 + tid)*4);
            f32x4 t3 = ld16_dc(hp + (3*512 + tid)*4);
            asm volatile("s_waitcnt vmcnt(0)" ::: "memory");
            __builtin_amdgcn_sched_barrier(0);
            *(f32x4*)&shh[(0*512 + tid)*4] = t0;
            *(f32x4*)&shh[(1*512 + tid)*4] = t1;
            *(f32x4*)&shh[(2*512 + tid)*4] = t2;
            *(f32x4*)&shh[(3*512 + tid)*4] = t3;
        }
        __syncthreads();

        #pragma unroll
        for (int p = 0; p < 2; ++p) {                     // 2 passes x 4 batches
            double acc[4][4];
            #pragma unroll
            for (int g = 0; g < 4; ++g)
                #pragma unroll
                for (int bb = 0; bb < 4; ++bb) acc[g][bb] = 0.0;
            #pragma unroll
            for (int jj = 0; jj < 2; ++jj) {
                const int kb = kh*512 + 4*lane + 256*jj;
                #pragma unroll
                for (int bb = 0; bb < 4; ++bb) {
                    const f32x4 hv = *(const f32x4*)&shh[(p*4 + bb)*HID + kb];
                    #pragma unroll
                    for (int g = 0; g < 4; ++g) {
                        acc[g][bb] = fma((double)w[g][jj].x, (double)hv.x, acc[g][bb]);
                        acc[g][bb] = fma((double)w[g][jj].y, (double)hv.y, acc[g][bb]);
                        acc[g][bb] = fma((double)w[g][jj].z, (double)hv.z, acc[g][bb]);
                        acc[g][bb] = fma((double)w[g][jj].w, (double)hv.w, acc[g][bb]);
                    }
                }
            }
            #pragma unroll
            for (int g = 0; g < 4; ++g)
                #pragma unroll
                for (int bb = 0; bb < 4; ++bb) {
                    double v = acc[g][bb];
                    #pragma unroll
                    for (int off = 32; off > 0; off >>= 1) v += __shfl_xor(v, off, 64);
                    acc[g][bb] = v;
                }
            if (lane == 0) {
                #pragma unroll
                for (int g = 0; g < 4; ++g)
                    #pragma unroll
                    for (int bb = 0; bb < 4; ++bb)
                        sred[ul][kh][g][bb] = acc[g][bb];
            }
            __syncthreads();
            if (kh == 1 && lane < 4) {
                const int b = p*4 + lane;
                const double* gr = G + (size_t)(b*SEQ + k)*4096;
                double tg[4];
                #pragma unroll
                for (int g = 0; g < 4; ++g)
                    tg[g] = sred[ul][0][g][lane] + sred[ul][1][g][lane]
                          + gr[g*HID + u] + (double)bias[g*HID + u];
                const double cc = exp(tg[1])*cbuf[b*HID + u] + exp(tg[0])*tanh(tg[2]);
                const double hh = tanh(cc) / (1.0 + exp(-tg[3]));
                cbuf[b*HID + u] = cc;
                __hip_atomic_store(&hbuf[(k & 1)*HB + b*HID + u], (float)hh,
                                   __ATOMIC_RELAXED, __HIP_MEMORY_SCOPE_AGENT);
                hout[(size_t)(b*SEQ + k)*HID + u] = (float)hh;
            }
            __syncthreads();                               // protect sred for next pass
        }
        if (coop) {
            __syncthreads();          // drains this block's h-stores (vmcnt(0) + s_barrier)
            if (tid == 0)
                __hip_atomic_store(&slots[bk], (unsigned)(k - k0 + 1),
                                   __ATOMIC_RELAXED, __HIP_MEMORY_SCOPE_AGENT);
        }
    }
}

// ---------------- GELU(exact) + residual + LayerNorm, f64 internals ----------------
__global__ __launch_bounds__(256)
void k_post(const float* __restrict__ y, const float* __restrict__ xin,
            const float* __restrict__ gamma, const float* __restrict__ beta,
            float* __restrict__ xout) {
    const int row = blockIdx.x;
    const int tid = threadIdx.x;
    const f32x4 v  = *(const f32x4*)(y   + (size_t)row*HID + tid*4);
    const f32x4 xr = *(const f32x4*)(xin + (size_t)row*HID + tid*4);
    double o[4]; double s = 0.0, q = 0.0;
    #pragma unroll
    for (int e = 0; e < 4; ++e) {
        const double t  = (double)v[e];
        const double ge = 0.5 * t * (1.0 + erf(t * 0.7071067811865476));
        const double u  = ge + (double)xr[e];
        o[e] = u; s += u; q += u*u;
    }
    #pragma unroll
    for (int off = 32; off > 0; off >>= 1) {
        s += __shfl_xor(s, off, 64);
        q += __shfl_xor(q, off, 64);
    }
    __shared__ double rs[4], rq[4];
    const int wv = tid >> 6, lane = tid & 63;
    if (lane == 0) { rs[wv] = s; rq[wv] = q; }
    __syncthreads();
    s = rs[0] + rs[1] + rs[2] + rs[3];
    q = rq[0] + rq[1] + rq[2] + rq[3];
    const double mu   = s * (1.0/HID);
    const double var  = q * (1.0/HID) - mu*mu;
    const double rstd = 1.0 / sqrt(var + 1e-5);
    f32x4 ov;
    #pragma unroll
    for (int e = 0; e < 4; ++e) {
        const int col = tid*4 + e;
        ov[e] = (float)((o[e] - mu)*rstd*(double)gamma[col] + (double)beta[col]);
    }
    *(f32x4*)(xout + (size_t)row*HID + tid*4) = ov;
}

// -------------------------------------------------------------------------
extern "C" void kernel_launch(void* const* d_in, const int* in_sizes, int n_in,
                              void* d_out, int out_size, void* d_ws, size_t ws_size,
                              hipStream_t stream) {
    const int*   idx   = (const int*)d_in[0];
    const float* emb   = (const float*)d_in[1];
    const float* w_ih  = (const float*)d_in[2];
    const float* w_hh  = (const float*)d_in[3];
    const float* bias  = (const float*)d_in[4];
    const float* ln_g  = (const float*)d_in[5];
    const float* ln_b  = (const float*)d_in[6];
    const float* out_w = (const float*)d_in[7];
    const float* out_b = (const float*)d_in[8];
    float* logits = (float*)d_out;

    char* ws = (char*)d_ws;
    size_t off = 0;
    auto alloc = [&](size_t bytes) -> char* {
        char* p = ws + off;
        off = (off + bytes + 255) & ~(size_t)255;
        return p;
    };
    const int ROWS = BATCH * SEQ;                       // 2048
    float*          X    = (float*)         alloc((size_t)ROWS*HID*4);
    unsigned short* XHI  = (unsigned short*)alloc((size_t)ROWS*HID*2);
    unsigned short* XLO  = (unsigned short*)alloc((size_t)ROWS*HID*2);
    char*           ST   =                  alloc(262144);
    char*           REG  = alloc((size_t)VOCAB*HID*2*2);                     // 131.1 MB
    // during blocks: G (67.1 MB) + H0 (8.4) + Y (8.4); final GEMM: OWHI+OWLO overlay
    double*         Gp   = (double*)REG;                                     // 67.1 MB
    float*          H0   = (float*)(REG + (size_t)ROWS*4096*8);              //  8.4 MB
    float*          Y    = (float*)(REG + (size_t)ROWS*4096*8 + (size_t)ROWS*HID*4);
    unsigned short* OWHI = (unsigned short*)REG;
    unsigned short* OWLO = (unsigned short*)(REG + (size_t)VOCAB*HID*2);

    float*    hbuf  = (float*)ST;                  // [2][8][1024] f32 parity  (64 KB)
    double*   cbuf  = (double*)(ST + 65536);       // [8][1024] f64            (64 KB)
    unsigned* slots = (unsigned*)(ST + 131072);    // [256] barrier            ( 1 KB)

    auto run_phase = [&](const float* W, const float* bs, const double* G,
                         float* hout) {
        hipMemsetAsync(ST, 0, 133120, stream);     // zero h parity + c + slots
        int k0 = 0, k1 = SEQ, coop = 1;
        void* ka[] = {(void*)&W, (void*)&bs, (void*)&G,
                      (void*)&hbuf, (void*)&cbuf, (void*)&hout, (void*)&slots,
                      (void*)&k0, (void*)&k1, (void*)&coop};
        hipError_t e = hipLaunchCooperativeKernel((const void*)k_scan_phase,
                                                  dim3(256), dim3(512), ka, 0, stream);
        if (e != hipSuccess) {                     // deterministic fallback
            for (int kk = 0; kk < SEQ; ++kk)
                k_scan_phase<<<256, 512, 0, stream>>>(W, bs, G, hbuf, cbuf, hout,
                                                      slots, kk, kk + 1, 0);
        }
    };

    k_embed<<<ROWS, 256, 0, stream>>>(idx, emb, X);

    for (int blk = 0; blk < 2; ++blk) {
        const float* wih0 = w_ih + (size_t)blk*2*4096*HID;
        const float* wih1 = wih0 + (size_t)4096*HID;
        const float* whh0 = w_hh + (size_t)blk*2*4096*HID;
        const float* whh1 = whh0 + (size_t)4096*HID;
        const float* b0 = bias + (size_t)blk*2*4096;
        const float* b1 = b0 + 4096;

        // G = x @ w_ih0^T (f64), phase A: layer-0 scan -> H0
        k_gemm_f64<<<(ROWS/64)*(4096/64), 256, 0, stream>>>(X, wih0, Gp,
                                                            ROWS, 4096, HID);
        run_phase(whh0, b0, Gp, H0);

        // G = H0 @ w_ih1^T (f64, overwrites consumed G), phase B: layer-1 -> Y
        k_gemm_f64<<<(ROWS/64)*(4096/64), 256, 0, stream>>>(H0, wih1, Gp,
                                                            ROWS, 4096, HID);
        run_phase(whh1, b1, Gp, Y);

        k_post<<<ROWS, 256, 0, stream>>>(Y, X, ln_g + blk*HID, ln_b + blk*HID, X);
    }

    // logits = x @ out_w^T + out_b in split-bf16 (~f32 accuracy; not amplified)
    k_cvt<<<1024, 256, 0, stream>>>(X, XHI, XLO, ROWS*HID);
    k_cvt<<<4096, 256, 0, stream>>>(out_w, OWHI, OWLO, VOCAB*HID);
    k_gemm3<<<16*250, 256, 0, stream>>>(XHI, XLO, OWHI, OWLO, logits, out_b,
                                        ROWS, VOCAB, HID);
}